// Round 5
// baseline (126.698 us; speedup 1.0000x reference)
//
#include <hip/hip_runtime.h>
#include <math.h>

typedef short short8 __attribute__((ext_vector_type(8)));
typedef float f32x4  __attribute__((ext_vector_type(4)));

constexpr int Ssz = 512, Dsz = 64, Lsz = 4, Bsz = 32;
constexpr int TI = 64, TJ = 64;   // i-tile, j-chunk

// Main-phase LDS: 10 dense [64][64] bf16 tiles, 16B-granule XOR swizzle (g ^= row&7).
// Row stride 128B == 0 mod 32 banks; the XOR spreads the 8 granules of each
// 8-row stripe across all 32 banks -> conflict-free b128 writes AND reads.
constexpr int TILE16 = 64 * 64;                 // shorts per tile (8192 B)
constexpr int XH16 = 0;                         // hi(X^T)  [d][j]
constexpr int XL16 = TILE16;                    // lo(X^T)
constexpr int AI16 = 2 * TILE16;                // 4 x AI[l][i][j] = A[j0+j][i0+i]
constexpr int AO16 = 6 * TILE16;                // 4 x AO[l][i][j] = A[i0+i][j0+j]
constexpr int SMEM_BYTES = 10 * TILE16 * 2;     // 81920 B -> exactly 2 blocks/CU

// epilogue overlay (float-indexed, main tiles dead by then; 35.8 KB < 80 KB)
constexpr int YBs = 69;                          // 69 == 5 mod 32 -> conflict-free column reads
constexpr int YB_f = 0;                          // [64][69] f32
constexpr int WBs = 68;
constexpr int WB_f = YB_f + 64 * YBs;            // [64][68] f32
constexpr int DG_f = WB_f + 64 * WBs;            // [64] deg
constexpr int WG_f = DG_f + 64;                  // [64] gate weights
constexpr int BB_f = WG_f + 64;                  // [64] bias

__device__ __forceinline__ unsigned short f2bf(float x) {
    union { float f; unsigned u; } v; v.f = x;
    unsigned r = v.u + 0x7FFFu + ((v.u >> 16) & 1u);   // RNE
    return (unsigned short)(r >> 16);
}

__global__ __launch_bounds__(512, 4)
void rfgcn_mfma(const float* __restrict__ X,      // [B][S][D]
                const int*   __restrict__ adj,    // [L][B][S][S]
                const float* __restrict__ nw,     // [B]
                const float* __restrict__ W_in,   // [L][D][D] (row = d_in)
                const float* __restrict__ b_in,   // [L][D]
                const float* __restrict__ wg_in,  // [L][D]
                const float* __restrict__ bg_in,  // [L]
                const float* __restrict__ W_out,
                const float* __restrict__ b_out,
                const float* __restrict__ wg_out,
                const float* __restrict__ bg_out,
                float* __restrict__ out)
{
    __shared__ __align__(16) char smem[SMEM_BYTES];
    short* sm16 = (short*)smem;
    float* smf  = (float*)smem;

    const int tid  = threadIdx.x;
    const int b    = blockIdx.y;
    const int i0   = blockIdx.x * TI;
    const int w    = tid >> 6;      // wave 0..7
    const int lane = tid & 63;
    const int dir  = w & 1;         // 0 = in (A^T), 1 = out (A)
    const int sw   = w >> 1;        // 16-row strip 0..3
    const int lm   = lane & 15;
    const int lg   = lane >> 4;     // k-group 0..3

    f32x4 acc[Lsz][4];              // [label][n-tile]
    f32x4 dacc[Lsz];                // degree accumulator
#pragma unroll
    for (int l = 0; l < Lsz; ++l) {
#pragma unroll
        for (int nt = 0; nt < 4; ++nt) acc[l][nt] = (f32x4){0.f, 0.f, 0.f, 0.f};
        dacc[l] = (f32x4){0.f, 0.f, 0.f, 0.f};
    }
    const short8 ones = {(short)0x3F80, (short)0x3F80, (short)0x3F80, (short)0x3F80,
                         (short)0x3F80, (short)0x3F80, (short)0x3F80, (short)0x3F80};

    const float* Xb = X + (size_t)b * Ssz * Dsz;

    for (int jc = 0; jc < Ssz / TJ; ++jc) {
        const int j0 = jc * TJ;
        __syncthreads();   // previous chunk's fragment reads done

        // ---- stage X^T hi/lo: thread owns column d=lane, rows j0+8w..+7 (coalesced 256B rows)
        {
            const int d = lane;
            float xv[8];
#pragma unroll
            for (int s = 0; s < 8; ++s) xv[s] = Xb[(size_t)(j0 + 8 * w + s) * Dsz + d];
            short8 hi, lo;
#pragma unroll
            for (int s = 0; s < 8; ++s) {
                unsigned short h = f2bf(xv[s]);
                union { unsigned u; float f; } hf; hf.u = ((unsigned)h) << 16;
                hi[s] = (short)h;
                lo[s] = (short)f2bf(xv[s] - hf.f);
            }
            const int g = w ^ (d & 7);
            *(short8*)(sm16 + XH16 + d * 64 + g * 8) = hi;
            *(short8*)(sm16 + XL16 + d * 64 + g * 8) = lo;
        }
        // ---- stage AI (transposed adjacency): thread owns col i=lane, rows j0+8w..+7
#pragma unroll
        for (int l = 0; l < Lsz; ++l) {
            const int* Ab = adj + ((size_t)l * Bsz + b) * Ssz * Ssz;
            int iv[8];
#pragma unroll
            for (int s = 0; s < 8; ++s) iv[s] = Ab[(size_t)(j0 + 8 * w + s) * Ssz + i0 + lane];
            short8 v;
#pragma unroll
            for (int s = 0; s < 8; ++s) v[s] = iv[s] ? (short)0x3F80 : (short)0;
            const int g = w ^ (lane & 7);
            *(short8*)(sm16 + AI16 + l * TILE16 + lane * 64 + g * 8) = v;
        }
        // ---- stage AO (direct adjacency): thread owns row r=tid>>3, granule c8=tid&7
#pragma unroll
        for (int l = 0; l < Lsz; ++l) {
            const int* Ab = adj + ((size_t)l * Bsz + b) * Ssz * Ssz;
            const int r = tid >> 3, c8 = tid & 7;
            const int4 p0 = *(const int4*)&Ab[(size_t)(i0 + r) * Ssz + j0 + 8 * c8];
            const int4 p1 = *(const int4*)&Ab[(size_t)(i0 + r) * Ssz + j0 + 8 * c8 + 4];
            short8 v;
            v[0] = p0.x ? (short)0x3F80 : (short)0;  v[1] = p0.y ? (short)0x3F80 : (short)0;
            v[2] = p0.z ? (short)0x3F80 : (short)0;  v[3] = p0.w ? (short)0x3F80 : (short)0;
            v[4] = p1.x ? (short)0x3F80 : (short)0;  v[5] = p1.y ? (short)0x3F80 : (short)0;
            v[6] = p1.z ? (short)0x3F80 : (short)0;  v[7] = p1.w ? (short)0x3F80 : (short)0;
            const int g = c8 ^ (r & 7);
            *(short8*)(sm16 + AO16 + l * TILE16 + r * 64 + g * 8) = v;
        }
        __syncthreads();

        // ---- 2 K-steps of 32
#pragma unroll
        for (int ks = 0; ks < 2; ++ks) {
            short8 bh[4], bl[4];
#pragma unroll
            for (int nt = 0; nt < 4; ++nt) {
                const int d = nt * 16 + lm;
                const int g = (4 * ks + lg) ^ (d & 7);
                bh[nt] = *(const short8*)(sm16 + XH16 + d * 64 + g * 8);
                bl[nt] = *(const short8*)(sm16 + XL16 + d * 64 + g * 8);
            }
            const int i_loc = 16 * sw + lm;
            const int ga = (4 * ks + lg) ^ (i_loc & 7);
            const int a_base = AI16 + dir * (4 * TILE16) + i_loc * 64 + ga * 8;
#pragma unroll
            for (int l = 0; l < Lsz; ++l) {
                const short8 af = *(const short8*)(sm16 + a_base + l * TILE16);
#pragma unroll
                for (int nt = 0; nt < 4; ++nt) {
                    acc[l][nt] = __builtin_amdgcn_mfma_f32_16x16x32_bf16(af, bh[nt], acc[l][nt], 0, 0, 0);
                    acc[l][nt] = __builtin_amdgcn_mfma_f32_16x16x32_bf16(af, bl[nt], acc[l][nt], 0, 0, 0);
                }
                dacc[l] = __builtin_amdgcn_mfma_f32_16x16x32_bf16(af, ones, dacc[l], 0, 0, 0);
            }
        }
    }

    // ================= epilogue: t = Y*W + deg*b; gate = Y*wg + deg*bg; fin += t*sigmoid(gate)
    const int ei  = tid & 63;          // output row within tile
    const int ecb = (tid >> 6) * 8;    // 8-column group
    float fin[8];
#pragma unroll
    for (int q = 0; q < 8; ++q) fin[q] = 0.f;

#pragma unroll
    for (int l = 0; l < Lsz; ++l) {
#pragma unroll
        for (int d2 = 0; d2 < 2; ++d2) {
            __syncthreads();   // previous consumers done before overwrite
            if (dir == d2) {   // this wave owns (strip sw, dir d2) rows of acc[l]
#pragma unroll
                for (int nt = 0; nt < 4; ++nt)
#pragma unroll
                    for (int r = 0; r < 4; ++r)
                        smf[YB_f + (16 * sw + 4 * lg + r) * YBs + nt * 16 + lm] = acc[l][nt][r];
                if (lm == 0)
#pragma unroll
                    for (int r = 0; r < 4; ++r)
                        smf[DG_f + 16 * sw + 4 * lg + r] = dacc[l][r];
            }
            // stage W (all threads)
            const float* Wp = (d2 ? W_out : W_in) + l * Dsz * Dsz;
            {
                const int r = tid >> 3, c8 = tid & 7;
                *(float4*)&smf[WB_f + r * WBs + 8 * c8]     = *(const float4*)&Wp[r * Dsz + 8 * c8];
                *(float4*)&smf[WB_f + r * WBs + 8 * c8 + 4] = *(const float4*)&Wp[r * Dsz + 8 * c8 + 4];
            }
            const float* wgp = (d2 ? wg_out : wg_in) + l * Dsz;
            const float* bp  = (d2 ? b_out  : b_in)  + l * Dsz;
            if (tid < 64)        smf[WG_f + tid]      = wgp[tid];
            else if (tid < 128)  smf[BB_f + tid - 64] = bp[tid - 64];
            const float bgs = (d2 ? bg_out : bg_in)[l];
            __syncthreads();

            const float dg = smf[DG_f + ei];
            float t[8];
#pragma unroll
            for (int q = 0; q < 8; ++q) t[q] = dg * smf[BB_f + ecb + q];
            float gate = dg * bgs;
#pragma unroll 4
            for (int e = 0; e < 64; ++e) {
                const float yv = smf[YB_f + ei * YBs + e];
                gate += yv * smf[WG_f + e];
#pragma unroll
                for (int q = 0; q < 8; ++q) t[q] += yv * smf[WB_f + e * WBs + ecb + q];
            }
            const float sg = 1.f / (1.f + expf(-gate));
#pragma unroll
            for (int q = 0; q < 8; ++q) fin[q] += t[q] * sg;
        }
    }

    const float inv = 1.f / (3.f * nw[b]);
    const float4 x0 = *(const float4*)&Xb[(size_t)(i0 + ei) * Dsz + ecb];
    const float4 x1 = *(const float4*)&Xb[(size_t)(i0 + ei) * Dsz + ecb + 4];
    float4 o0, o1;
    o0.x = (x0.x + fin[0]) * inv;  o0.y = (x0.y + fin[1]) * inv;
    o0.z = (x0.z + fin[2]) * inv;  o0.w = (x0.w + fin[3]) * inv;
    o1.x = (x1.x + fin[4]) * inv;  o1.y = (x1.y + fin[5]) * inv;
    o1.z = (x1.z + fin[6]) * inv;  o1.w = (x1.w + fin[7]) * inv;
    float* op = out + ((size_t)b * Ssz + i0 + ei) * Dsz + ecb;
    *(float4*)op       = o0;
    *(float4*)(op + 4) = o1;
}

extern "C" void kernel_launch(void* const* d_in, const int* in_sizes, int n_in,
                              void* d_out, int out_size, void* d_ws, size_t ws_size,
                              hipStream_t stream)
{
    const float* X      = (const float*)d_in[0];
    const int*   adj    = (const int*)  d_in[1];
    const float* nw     = (const float*)d_in[2];
    const float* W_in   = (const float*)d_in[3];
    const float* b_in   = (const float*)d_in[4];
    const float* wg_in  = (const float*)d_in[5];
    const float* bg_in  = (const float*)d_in[6];
    const float* W_out  = (const float*)d_in[7];
    const float* b_out  = (const float*)d_in[8];
    const float* wg_out = (const float*)d_in[9];
    const float* bg_out = (const float*)d_in[10];
    float* out = (float*)d_out;

    dim3 grid(Ssz / TI, Bsz);   // (8, 32) = 256 blocks
    dim3 block(512);
    hipLaunchKernelGGL(rfgcn_mfma, grid, block, 0, stream,
                       X, adj, nw, W_in, b_in, wg_in, bg_in,
                       W_out, b_out, wg_out, bg_out, out);
}

// Round 8
// 77.939 us; speedup vs baseline: 1.6256x; 1.6256x over previous
//
#include <hip/hip_runtime.h>
#include <math.h>

typedef short s16x4  __attribute__((ext_vector_type(4)));
typedef short short8 __attribute__((ext_vector_type(8)));
typedef float f32x4  __attribute__((ext_vector_type(4)));

constexpr int Ssz = 512, Dsz = 64, Lsz = 4, Bsz = 32;
constexpr int TI = 32, TJ = 64;   // i-tile (32 -> 512 blocks = 2 blocks/CU), j-chunk

// Main-phase LDS: dense bf16 tiles with 16B-granule XOR swizzle (g ^= row&7).
// Row stride 128B == 0 mod 32 banks; XOR spreads granules across banks ->
// uniform (minimum) bank usage for all b64/b128 writes and b128 fragment reads.
constexpr int XT16 = 0;                          // X^T [64 d][64 j] bf16 (hi-only)
constexpr int AI16 = 64 * 64;                    // 4 x [32 i][64 j]: AI[l][i][j] = A[j0+j][i0+i]
constexpr int AO16 = AI16 + 4 * 32 * 64;         // 4 x [32 i][64 j]: AO[l][i][j] = A[i0+i][j0+j]
constexpr int SMEM_BYTES = (AO16 + 4 * 32 * 64) * 2;   // 40960 B -> 2 blocks/CU (grid-capped)

// epilogue overlay (float-indexed; main tiles dead by then; 27.0 KB < 40 KB)
constexpr int YBs = 69;                          // 69 == 5 mod 32 -> conflict-free column reads
constexpr int YB_f = 0;                          // [32][69] f32
constexpr int WBs = 68;
constexpr int WB_f = YB_f + 32 * YBs;            // [64][68] f32
constexpr int DG_f = WB_f + 64 * WBs;            // [32] deg
constexpr int WG_f = DG_f + 64;                  // [64] gate weights
constexpr int BB_f = WG_f + 64;                  // [64] bias

__device__ __forceinline__ unsigned short f2bf(float x) {
    union { float f; unsigned u; } v; v.f = x;
    unsigned r = v.u + 0x7FFFu + ((v.u >> 16) & 1u);   // RNE
    return (unsigned short)(r >> 16);
}

__global__ __launch_bounds__(512, 4)
void rfgcn_mfma(const float* __restrict__ X,      // [B][S][D]
                const int*   __restrict__ adj,    // [L][B][S][S]
                const float* __restrict__ nw,     // [B]
                const float* __restrict__ W_in,   // [L][D][D] (row = d_in)
                const float* __restrict__ b_in,   // [L][D]
                const float* __restrict__ wg_in,  // [L][D]
                const float* __restrict__ bg_in,  // [L]
                const float* __restrict__ W_out,
                const float* __restrict__ b_out,
                const float* __restrict__ wg_out,
                const float* __restrict__ bg_out,
                float* __restrict__ out)
{
    __shared__ __align__(16) char smem[SMEM_BYTES];
    short* sm16 = (short*)smem;
    float* smf  = (float*)smem;

    const int tid  = threadIdx.x;
    const int b    = blockIdx.y;
    const int i0   = blockIdx.x * TI;
    const int w    = tid >> 6;        // wave 0..7
    const int lane = tid & 63;
    const int dir   = w & 1;          // 0 = in (A^T), 1 = out (A)
    const int strip = (w >> 1) & 1;   // 16-row strip 0..1
    const int lh    = w >> 2;         // label-half 0..1 (labels 2lh, 2lh+1)
    const int lm   = lane & 15;
    const int lg   = lane >> 4;       // k-group 0..3

    f32x4 acc[2][4];                  // [label-within-half][n-tile]
    f32x4 dacc[2];                    // degree accumulator
#pragma unroll
    for (int al = 0; al < 2; ++al) {
#pragma unroll
        for (int nt = 0; nt < 4; ++nt) acc[al][nt] = (f32x4){0.f, 0.f, 0.f, 0.f};
        dacc[al] = (f32x4){0.f, 0.f, 0.f, 0.f};
    }
    const short8 ones = {(short)0x3F80, (short)0x3F80, (short)0x3F80, (short)0x3F80,
                         (short)0x3F80, (short)0x3F80, (short)0x3F80, (short)0x3F80};

    const float* Xb = X + (size_t)b * Ssz * Dsz;

    for (int jc = 0; jc < Ssz / TJ; ++jc) {
        const int j0 = jc * TJ;
        __syncthreads();   // previous chunk's fragment reads done

        // ---- stage X^T (bf16 hi only): thread owns col d=lane, rows j0+8w..+7
        {
            const int d = lane;
            float xv[8];
#pragma unroll
            for (int s = 0; s < 8; ++s) xv[s] = Xb[(size_t)(j0 + 8 * w + s) * Dsz + d];
            short8 hi;
#pragma unroll
            for (int s = 0; s < 8; ++s) hi[s] = (short)f2bf(xv[s]);
            const int g = w ^ (d & 7);
            *(short8*)(sm16 + XT16 + d * 64 + g * 8) = hi;
        }
        // ---- stage AI (transposed adjacency): thread owns col i=tid&31, j-quad jq=tid>>5
#pragma unroll
        for (int l = 0; l < Lsz; ++l) {
            const int* Ab = adj + ((size_t)l * Bsz + b) * Ssz * Ssz;
            const int ii = tid & 31, jq = tid >> 5;
            int iv[4];
#pragma unroll
            for (int s = 0; s < 4; ++s) iv[s] = Ab[(size_t)(j0 + jq * 4 + s) * Ssz + i0 + ii];
            s16x4 v;
#pragma unroll
            for (int s = 0; s < 4; ++s) v[s] = iv[s] ? (short)0x3F80 : (short)0;
            const int g = (jq >> 1) ^ (ii & 7);
            *(s16x4*)(sm16 + AI16 + l * 2048 + ii * 64 + g * 8 + (jq & 1) * 4) = v;
        }
        // ---- stage AO (direct adjacency): thread owns row r=tid>>4, j-quad c4=tid&15
#pragma unroll
        for (int l = 0; l < Lsz; ++l) {
            const int* Ab = adj + ((size_t)l * Bsz + b) * Ssz * Ssz;
            const int r = tid >> 4, c4 = tid & 15;
            const int4 p = *(const int4*)&Ab[(size_t)(i0 + r) * Ssz + j0 + c4 * 4];
            s16x4 v;
            v[0] = p.x ? (short)0x3F80 : (short)0;  v[1] = p.y ? (short)0x3F80 : (short)0;
            v[2] = p.z ? (short)0x3F80 : (short)0;  v[3] = p.w ? (short)0x3F80 : (short)0;
            const int g = (c4 >> 1) ^ (r & 7);
            *(s16x4*)(sm16 + AO16 + l * 2048 + r * 64 + g * 8 + (c4 & 1) * 4) = v;
        }
        __syncthreads();

        // ---- 2 K-steps of 32
#pragma unroll
        for (int ks = 0; ks < 2; ++ks) {
            short8 bh[4];
#pragma unroll
            for (int nt = 0; nt < 4; ++nt) {
                const int d = nt * 16 + lm;
                const int g = (4 * ks + lg) ^ (d & 7);
                bh[nt] = *(const short8*)(sm16 + XT16 + d * 64 + g * 8);
            }
            const int i_loc = 16 * strip + lm;
            const int ga = (4 * ks + lg) ^ (i_loc & 7);
            const int a_off = (dir ? AO16 : AI16) + i_loc * 64 + ga * 8;
#pragma unroll
            for (int al = 0; al < 2; ++al) {
                const int l = 2 * lh + al;
                const short8 af = *(const short8*)(sm16 + a_off + l * 2048);
#pragma unroll
                for (int nt = 0; nt < 4; ++nt)
                    acc[al][nt] = __builtin_amdgcn_mfma_f32_16x16x32_bf16(af, bh[nt], acc[al][nt], 0, 0, 0);
                dacc[al] = __builtin_amdgcn_mfma_f32_16x16x32_bf16(af, ones, dacc[al], 0, 0, 0);
            }
        }
    }

    // ================= epilogue: t = Y*W + deg*b; gate = Y*wg + deg*bg; fin += t*sigmoid(gate)
    const int ei  = tid & 31;          // output row within tile
    const int ecg = tid >> 5;          // 4-column group 0..15
    float fin[4];
#pragma unroll
    for (int q = 0; q < 4; ++q) fin[q] = 0.f;

#pragma unroll
    for (int l = 0; l < Lsz; ++l) {
#pragma unroll
        for (int d2 = 0; d2 < 2; ++d2) {
            __syncthreads();   // previous consumers done before overwrite
            if (dir == d2 && lh == (l >> 1)) {   // this wave owns (strip, d2, label l)
                const int al = l & 1;
#pragma unroll
                for (int nt = 0; nt < 4; ++nt)
#pragma unroll
                    for (int r = 0; r < 4; ++r)
                        smf[YB_f + (16 * strip + 4 * lg + r) * YBs + nt * 16 + lm] = acc[al][nt][r];
                if (lm == 0)
#pragma unroll
                    for (int r = 0; r < 4; ++r)
                        smf[DG_f + 16 * strip + 4 * lg + r] = dacc[al][r];
            }
            // stage W (all threads)
            const float* Wp = (d2 ? W_out : W_in) + l * Dsz * Dsz;
            {
                const int r = tid >> 3, c8 = tid & 7;
                *(float4*)&smf[WB_f + r * WBs + 8 * c8]     = *(const float4*)&Wp[r * Dsz + 8 * c8];
                *(float4*)&smf[WB_f + r * WBs + 8 * c8 + 4] = *(const float4*)&Wp[r * Dsz + 8 * c8 + 4];
            }
            const float* wgp = (d2 ? wg_out : wg_in) + l * Dsz;
            const float* bp  = (d2 ? b_out  : b_in)  + l * Dsz;
            if (tid < 64)        smf[WG_f + tid]      = wgp[tid];
            else if (tid < 128)  smf[BB_f + tid - 64] = bp[tid - 64];
            const float bgs = (d2 ? bg_out : bg_in)[l];
            __syncthreads();

            const float dg = smf[DG_f + ei];
            float t[4];
#pragma unroll
            for (int q = 0; q < 4; ++q) t[q] = dg * smf[BB_f + 4 * ecg + q];
            float gate = dg * bgs;
#pragma unroll 4
            for (int e = 0; e < 64; ++e) {
                const float yv = smf[YB_f + ei * YBs + e];
                gate += yv * smf[WG_f + e];
#pragma unroll
                for (int q = 0; q < 4; ++q) t[q] += yv * smf[WB_f + e * WBs + 4 * ecg + q];
            }
            const float sg = 1.f / (1.f + expf(-gate));
#pragma unroll
            for (int q = 0; q < 4; ++q) fin[q] += t[q] * sg;
        }
    }

    const float inv = 1.f / (3.f * nw[b]);
    const float4 xv = *(const float4*)&Xb[(size_t)(i0 + ei) * Dsz + 4 * ecg];
    float4 o;
    o.x = (xv.x + fin[0]) * inv;
    o.y = (xv.y + fin[1]) * inv;
    o.z = (xv.z + fin[2]) * inv;
    o.w = (xv.w + fin[3]) * inv;
    *(float4*)(out + ((size_t)b * Ssz + i0 + ei) * Dsz + 4 * ecg) = o;
}

extern "C" void kernel_launch(void* const* d_in, const int* in_sizes, int n_in,
                              void* d_out, int out_size, void* d_ws, size_t ws_size,
                              hipStream_t stream)
{
    const float* X      = (const float*)d_in[0];
    const int*   adj    = (const int*)  d_in[1];
    const float* nw     = (const float*)d_in[2];
    const float* W_in   = (const float*)d_in[3];
    const float* b_in   = (const float*)d_in[4];
    const float* wg_in  = (const float*)d_in[5];
    const float* bg_in  = (const float*)d_in[6];
    const float* W_out  = (const float*)d_in[7];
    const float* b_out  = (const float*)d_in[8];
    const float* wg_out = (const float*)d_in[9];
    const float* bg_out = (const float*)d_in[10];
    float* out = (float*)d_out;

    dim3 grid(Ssz / TI, Bsz);   // (16, 32) = 512 blocks -> 2 blocks/CU
    dim3 block(512);
    hipLaunchKernelGGL(rfgcn_mfma, grid, block, 0, stream,
                       X, adj, nw, W_in, b_in, wg_in, bg_in,
                       W_out, b_out, wg_out, bg_out, out);
}